// Round 7
// baseline (1911.299 us; speedup 1.0000x reference)
//
#include <hip/hip_runtime.h>

#define PI_F 3.14159265358979323846f

constexpr int L_ = 16384;   // H*W
constexpr int PD_ = 32768;  // P*P*C

__device__ __forceinline__ float sigmoidf_(float x){ return 1.f/(1.f+__expf(-x)); }
__device__ __forceinline__ float softplusf_(float x){ return x>20.f ? x : log1pf(__expf(x)); }
__device__ __forceinline__ float geluf_(float x){ return 0.5f*x*(1.f+erff(x*0.70710678118654752f)); }

__device__ __forceinline__ float2 block_reduce2(float s, float ss){
  __shared__ float r1[256], r2[256];
  int tid = threadIdx.x;
  r1[tid]=s; r2[tid]=ss; __syncthreads();
  for(int o=128;o>0;o>>=1){ if(tid<o){ r1[tid]+=r1[tid+o]; r2[tid]+=r2[tid+o]; } __syncthreads(); }
  float2 out; out.x=r1[0]; out.y=r2[0]; __syncthreads();
  return out;
}

// ---------------- patch embed ----------------
__global__ __launch_bounds__(256) void k_pesum(const float* __restrict__ img, float* __restrict__ stats){
  int blk=blockIdx.x; int m=blk>>3, sl=blk&7;
  int b=m>>4, n=m&15, ih=n>>2, iw=n&3;
  int tid=threadIdx.x;
  const float* base=img+(size_t)b*32*L_;
  float s=0.f, ss=0.f;
  for (int i=tid;i<4096;i+=256){
    int j=sl*4096+i;
    int c=j>>10, p1=(j>>5)&31, p2=j&31;
    float v=base[(size_t)c*L_+(ih*32+p1)*128+iw*32+p2];
    s+=v; ss+=v*v;
  }
  float2 r=block_reduce2(s,ss);
  if (tid==0){ atomicAdd(&stats[m*2],r.x); atomicAdd(&stats[m*2+1],r.y); }
}

// + extra blocks zero tA
__global__ __launch_bounds__(256) void k_penorm(const float* __restrict__ img, const float* __restrict__ stats,
                                                const float* __restrict__ g, const float* __restrict__ bv,
                                                float* __restrict__ xn, float4* __restrict__ zbuf, int zn4){
  int blk=blockIdx.x;
  if (blk>=256){
    int i=(blk-256)*256+threadIdx.x;
    if (i<zn4) zbuf[i]=make_float4(0.f,0.f,0.f,0.f);
    return;
  }
  int m=blk>>3, sl=blk&7;
  int b=m>>4, n=m&15, ih=n>>2, iw=n&3;
  int tid=threadIdx.x;
  const float* base=img+(size_t)b*32*L_;
  float mean=stats[m*2]/(float)PD_;
  float var =stats[m*2+1]/(float)PD_-mean*mean;
  float inv =1.f/sqrtf(var+1e-5f);
  for (int i=tid;i<4096;i+=256){
    int j=sl*4096+i;
    int c=j>>10, p1=(j>>5)&31, p2=j&31;
    float v=base[(size_t)c*L_+(ih*32+p1)*128+iw*32+p2];
    int k=(p1*32+p2)*32+c;
    xn[(size_t)m*PD_+k]=(v-mean)*inv*g[k]+bv[k];
  }
}

// split-K skinny GEMM
template<int KC, int MODE>
__global__ __launch_bounds__(256) void k_gemm_sk(const float* __restrict__ A, const float* __restrict__ Bw,
                                                 const float* __restrict__ bias, float* __restrict__ C,
                                                 int N, int K){
  __shared__ float As[32][KC];
  int tid=threadIdx.x, tx=tid&63, ty=tid>>6;
  int n = blockIdx.x*64+tx;
  int k0 = blockIdx.y*KC;
  for (int i=tid;i<32*KC;i+=256){
    int r=i/KC, c=i%KC;
    float v=A[(size_t)r*K + k0 + c];
    if (MODE==1) v=geluf_(v);
    As[r][c]=v;
  }
  __syncthreads();
  float acc[8]={0,0,0,0,0,0,0,0};
  for (int kk=0;kk<KC;kk+=4){
    float b0=Bw[(size_t)(k0+kk)*N+n],   b1=Bw[(size_t)(k0+kk+1)*N+n];
    float b2=Bw[(size_t)(k0+kk+2)*N+n], b3=Bw[(size_t)(k0+kk+3)*N+n];
    #pragma unroll
    for (int r=0;r<8;r++){
      const float4 a=*(const float4*)&As[ty*8+r][kk];
      acc[r]+=a.x*b0+a.y*b1+a.z*b2+a.w*b3;
    }
  }
  bool addb = (bias!=nullptr) && (blockIdx.y==0);
  #pragma unroll
  for (int r=0;r<8;r++){
    int m=ty*8+r;
    float v=acc[r]+(addb?bias[n]:0.f);
    if (MODE==2){
      int b=m>>4, ih=(m>>2)&3, iw=m&3;
      int cu=n>>10, f1=(n>>5)&31, f2=n&31;
      atomicAdd(&C[((size_t)(b*4+cu)*128+ih*32+f1)*128+iw*32+f2], v);
    } else {
      atomicAdd(&C[(size_t)m*N+n], v);
    }
  }
}

__global__ __launch_bounds__(256) void k_pe_post(float* __restrict__ t,
                                                 const float* __restrict__ g, const float* __restrict__ bv,
                                                 const float* __restrict__ pos){
  int m=blockIdx.x, tid=threadIdx.x;
  float v0 = t[m*512+tid];
  float v1 = t[m*512+256+tid];
  float2 r = block_reduce2(v0+v1, v0*v0+v1*v1);
  float mean=r.x/512.f, var=r.y/512.f-mean*mean, inv=1.f/sqrtf(var+1e-5f);
  int n = m&15;
  t[m*512+tid]     = (v0-mean)*inv*g[tid]+bv[tid]         + pos[n*512+tid];
  t[m*512+256+tid] = (v1-mean)*inv*g[256+tid]+bv[256+tid] + pos[n*512+256+tid];
}

// LN + optional zero of another buffer (extra blocks)
__global__ __launch_bounds__(256) void k_ln_tokz(const float* __restrict__ src, const float* __restrict__ g,
                                                 const float* __restrict__ bv, float* __restrict__ dst,
                                                 float4* __restrict__ zbuf, int zn4){
  int blk=blockIdx.x;
  if (blk>=32){
    int i=(blk-32)*256+threadIdx.x;
    if (i<zn4) zbuf[i]=make_float4(0.f,0.f,0.f,0.f);
    return;
  }
  int m=blk, tid=threadIdx.x;
  float v0=src[m*512+tid], v1=src[m*512+256+tid];
  float2 r=block_reduce2(v0+v1, v0*v0+v1*v1);
  float mean=r.x/512.f, var=r.y/512.f-mean*mean, inv=1.f/sqrtf(var+1e-5f);
  dst[m*512+tid]     =(v0-mean)*inv*g[tid]+bv[tid];
  dst[m*512+256+tid] =(v1-mean)*inv*g[256+tid]+bv[256+tid];
}

__global__ void k_addpos(const float* __restrict__ t, const float* __restrict__ pos, float* __restrict__ dst){
  int i = blockIdx.x*256+threadIdx.x;
  int m=i>>9, j=i&511;
  dst[i]=t[i]+pos[(m&15)*512+j];
}

__global__ __launch_bounds__(256) void k_attn(const float* __restrict__ qkv, float* __restrict__ outb){
  int bh=blockIdx.x, b=bh>>3, h=bh&7, tid=threadIdx.x;
  __shared__ float q[16][64], kk[16][64], vv[16][64], pp[16][16];
  for (int i=tid;i<1024;i+=256){
    int row=i>>6, d=i&63;
    const float* src=qkv + (size_t)(b*16+row)*1536 + h*64+d;
    q[row][d]=src[0]; kk[row][d]=src[512]; vv[row][d]=src[1024];
  }
  __syncthreads();
  int i=tid>>4, j=tid&15;
  float s=0.f;
  #pragma unroll
  for (int d=0;d<64;d++) s+=q[i][d]*kk[j][d];
  s*=0.125f;
  float mx=s;
  for (int o=8;o>0;o>>=1) mx=fmaxf(mx,__shfl_xor(mx,o,16));
  float e=__expf(s-mx), sm=e;
  for (int o=8;o>0;o>>=1) sm+=__shfl_xor(sm,o,16);
  pp[i][j]=e/sm;
  __syncthreads();
  int d=tid&63;
  for (int pass=0;pass<4;pass++){
    int row=pass*4+(tid>>6);
    float acc=0.f;
    #pragma unroll
    for (int jj=0;jj<16;jj++) acc+=pp[row][jj]*vv[jj][d];
    outb[(size_t)(b*16+row)*512 + h*64+d]=acc;
  }
}

// ---------------- SS2D ----------------
__global__ __launch_bounds__(256) void k_xz(const float* __restrict__ ksp, const float* __restrict__ w,
                                            const float* __restrict__ bv, float* __restrict__ xz){
  int blk=blockIdx.x; int b=blk>>6; int p0=(blk&63)*256; int tid=threadIdx.x;
  __shared__ float lin[32][256];
  __shared__ float lw[2048];
  for (int i=tid;i<2048;i+=256) lw[i]=w[i];
  for (int i=tid;i<8192;i+=256){ int c=i>>8, p=i&255; lin[c][p]=ksp[(size_t)(b*32+c)*L_+p0+p]; }
  __syncthreads();
  float xv[32];
  #pragma unroll
  for (int c=0;c<32;c++) xv[c]=lin[c][tid];
  for (int e=0;e<64;e++){
    float a=bv[e];
    #pragma unroll
    for (int c=0;c<32;c++) a+=xv[c]*lw[c*64+e];
    xz[(size_t)(b*64+e)*L_+p0+tid]=a;
  }
}

__global__ void k_dwconv(const float* __restrict__ xz, const float* __restrict__ w,
                         const float* __restrict__ bv, float* __restrict__ xs0){
  int i=blockIdx.x*256+threadIdx.x;
  int p=i&16383; int d=(i>>14)&31; int b=i>>19;
  int h=p>>7, ww=p&127;
  const float* src=xz+(size_t)(b*64+d)*L_;
  float acc=bv[d];
  for (int ky=0;ky<3;ky++){
    int hh=h+ky-1; if(hh<0||hh>127) continue;
    for (int kx=0;kx<3;kx++){
      int wx=ww+kx-1; if(wx<0||wx>127) continue;
      acc+=src[hh*128+wx]*w[d*9+ky*3+kx];
    }
  }
  xs0[(size_t)(b*32+d)*L_+p]=acc*sigmoidf_(acc);
}

__global__ __launch_bounds__(256) void k_transpose(const float* __restrict__ src, float* __restrict__ dst){
  __shared__ float tile[32][33];
  int z=blockIdx.z;
  int h0=blockIdx.y*32, w0=blockIdx.x*32;
  int tid=threadIdx.x, tx=tid&31, ty=tid>>5;
  const float* s=src+(size_t)z*L_;
  float* d=dst+(size_t)z*L_;
  for (int r=ty;r<32;r+=8) tile[r][tx]=s[(h0+r)*128+w0+tx];
  __syncthreads();
  for (int r=ty;r<32;r+=8) d[(w0+r)*128+h0+tx]=tile[tx][r];
}

__global__ __launch_bounds__(256) void k_dbl(const float* __restrict__ xs0, const float* __restrict__ xs0T,
                                             const float* __restrict__ xproj, float* __restrict__ dbl){
  int bk=blockIdx.y; int b=bk>>2, k=bk&3;
  int l0=blockIdx.x*256, tid=threadIdx.x;
  const float* src=(k&1)?xs0T:xs0;
  __shared__ float xv[32][256];
  __shared__ float xp[576];
  for (int i=tid;i<576;i+=256) xp[i]=xproj[k*576+i];
  for (int i=tid;i<8192;i+=256){
    int dd=i>>8, p=i&255; int l=l0+p; int li=(k<2)?l:(16383-l);
    xv[dd][p]=src[(size_t)(b*32+dd)*L_+li];
  }
  __syncthreads();
  float xr[32];
  #pragma unroll
  for (int dd=0;dd<32;dd++) xr[dd]=xv[dd][tid];
  float* out=&dbl[((size_t)(b*4+k)*L_ + l0+tid)*18];
  for (int c=0;c<18;c++){
    float a=0.f;
    #pragma unroll
    for (int dd=0;dd<32;dd++) a+=xr[dd]*xp[dd*18+c];
    out[c]=a;
  }
}

// ---- chunked 3-phase selective scan ----
__global__ __launch_bounds__(256) void k_scan1(const float* __restrict__ dbl, const float* __restrict__ xs0,
                                               const float* __restrict__ xs0T, const float* __restrict__ dtw,
                                               const float* __restrict__ dtb, const float* __restrict__ Alog,
                                               float2* __restrict__ sm){
  int blk=blockIdx.x; int bk=blk>>7, c=blk&127;
  int b=bk>>2, k=bk&3;
  int tid=threadIdx.x, d=tid>>3, s=tid&7;
  __shared__ float ed[128][18];
  __shared__ float2 du[32][129];
  const float* dbase=dbl+((size_t)bk*L_+c*128)*18;
  for (int i=tid;i<2304;i+=256) ((float*)ed)[i]=dbase[i];
  __syncthreads();
  const float* src=(k&1)?xs0T:xs0;
  bool rev=(k>=2);
  for (int i=tid;i<4096;i+=256){
    int dd=i>>7, j=i&127; int l=c*128+j;
    float xsv=src[(size_t)(b*32+dd)*L_+(rev?(16383-l):l)];
    float w0=dtw[(k*2+0)*32+dd], w1=dtw[(k*2+1)*32+dd], bb=dtb[k*32+dd];
    float dt=softplusf_(ed[j][0]*w0+ed[j][1]*w1+bb);
    du[dd][j]=make_float2(dt, dt*xsv);
  }
  __syncthreads();
  float Av=-__expf(Alog[(k*32+d)*8+s]);
  float P=1.f, Q=0.f;
  for (int j=0;j<128;j++){
    float2 v=du[d][j];
    float a=__expf(v.x*Av);
    Q=a*Q+v.y*ed[j][2+s];
    P*=a;
  }
  sm[((size_t)bk*128+c)*256+tid]=make_float2(P,Q);
}

__global__ __launch_bounds__(256) void k_scan2(const float2* __restrict__ sm, float* __restrict__ pre){
  int bk=blockIdx.x, tid=threadIdx.x;
  float run=0.f;
  for (int cb=0; cb<128; cb+=16){
    float2 v[16];
    #pragma unroll
    for (int t=0;t<16;t++) v[t]=sm[((size_t)bk*128+cb+t)*256+tid];
    #pragma unroll
    for (int t=0;t<16;t++){
      pre[((size_t)bk*128+cb+t)*256+tid]=run;
      run=v[t].x*run+v[t].y;
    }
  }
}

__global__ __launch_bounds__(256) void k_scan3(const float* __restrict__ dbl, const float* __restrict__ xs0,
                                               const float* __restrict__ xs0T, const float* __restrict__ dtw,
                                               const float* __restrict__ dtb, const float* __restrict__ Alog,
                                               const float* __restrict__ pre, float* __restrict__ ys){
  int blk=blockIdx.x; int bk=blk>>7, c=blk&127;
  int b=bk>>2, k=bk&3;
  int tid=threadIdx.x, d=tid>>3, s=tid&7;
  __shared__ float ed[128][18];
  __shared__ float2 du[32][129];
  const float* dbase=dbl+((size_t)bk*L_+c*128)*18;
  for (int i=tid;i<2304;i+=256) ((float*)ed)[i]=dbase[i];
  __syncthreads();
  const float* src=(k&1)?xs0T:xs0;
  bool rev=(k>=2);
  for (int i=tid;i<4096;i+=256){
    int dd=i>>7, j=i&127; int l=c*128+j;
    float xsv=src[(size_t)(b*32+dd)*L_+(rev?(16383-l):l)];
    float w0=dtw[(k*2+0)*32+dd], w1=dtw[(k*2+1)*32+dd], bb=dtb[k*32+dd];
    float dt=softplusf_(ed[j][0]*w0+ed[j][1]*w1+bb);
    du[dd][j]=make_float2(dt, dt*xsv);
  }
  __syncthreads();
  float Av=-__expf(Alog[(k*32+d)*8+s]);
  float h=pre[((size_t)bk*128+c)*256+tid];
  float* yout=ys+((size_t)bk*32+d)*L_+c*128;
  for (int j=0;j<128;j++){
    float2 v=du[d][j];
    float a=__expf(v.x*Av);
    h=a*h+v.y*ed[j][2+s];
    float yp=h*ed[j][10+s];
    yp+=__shfl_xor(yp,1,8);
    yp+=__shfl_xor(yp,2,8);
    yp+=__shfl_xor(yp,4,8);
    if (s==0) yout[j]=yp;
  }
}

__global__ __launch_bounds__(256) void k_ycomb(const float* __restrict__ ys, const float* __restrict__ xz,
                                               const float* __restrict__ xs0, const float* __restrict__ Dp,
                                               const float* __restrict__ g, const float* __restrict__ bv,
                                               const float* __restrict__ ow, const float* __restrict__ ob,
                                               float* __restrict__ oss){
  int blk=blockIdx.x; int b=blk>>7; int pg=blk&127;
  int tid=threadIdx.x; int pos=tid&127; int team=tid>>7;
  int p=pg*128+pos;
  int lt=pos*128+pg;
  __shared__ float lw[640]; __shared__ float lb[20]; __shared__ float lg[32], lbv[32], lD[32];
  __shared__ float red[2][2][128];
  __shared__ float prj[128][21];
  for (int i=tid;i<640;i+=256) lw[i]=ow[i];
  if (tid<20) lb[tid]=ob[tid];
  if (tid<32){ lg[tid]=g[tid]; lbv[tid]=bv[tid]; lD[tid]=Dp[tid]+Dp[32+tid]+Dp[64+tid]+Dp[96+tid]; }
  __syncthreads();
  size_t base=(size_t)b*128*L_;
  int d0=team*16;
  float y[16];
  float s=0.f, ss=0.f;
  #pragma unroll
  for (int dd=0;dd<16;dd++){
    int d=d0+dd;
    float v=ys[base+(size_t)(0*32+d)*L_+p] + ys[base+(size_t)(2*32+d)*L_+16383-p]
          + ys[base+(size_t)(1*32+d)*L_+lt] + ys[base+(size_t)(3*32+d)*L_+16383-lt]
          + lD[d]*xs0[(size_t)(b*32+d)*L_+p];
    y[dd]=v; s+=v; ss+=v*v;
  }
  red[team][0][pos]=s; red[team][1][pos]=ss;
  __syncthreads();
  float S=red[0][0][pos]+red[1][0][pos];
  float SS=red[0][1][pos]+red[1][1][pos];
  float mean=S/32.f, var=SS/32.f-mean*mean, inv=1.f/sqrtf(var+1e-5f);
  float pc[20];
  #pragma unroll
  for (int c2=0;c2<20;c2++) pc[c2]=0.f;
  #pragma unroll
  for (int dd=0;dd<16;dd++){
    int d=d0+dd;
    float yn=(y[dd]-mean)*inv*lg[d]+lbv[d];
    float zv=xz[(size_t)(b*64+32+d)*L_+p];
    float t2=yn*(zv*sigmoidf_(zv));
    #pragma unroll
    for (int c2=0;c2<20;c2++) pc[c2]+=t2*lw[d*20+c2];
  }
  if (team==1){
    #pragma unroll
    for (int c2=0;c2<20;c2++) prj[pos][c2]=pc[c2];
  }
  __syncthreads();
  if (team==0){
    #pragma unroll
    for (int c2=0;c2<20;c2++) oss[(size_t)(b*20+c2)*L_+p]=lb[c2]+pc[c2]+prj[pos][c2];
  }
}

__global__ void k_concat(const float* __restrict__ x, const float* __restrict__ img,
                         const float* __restrict__ oss, float* __restrict__ xc){
  int i=blockIdx.x*256+threadIdx.x;
  int p=i&16383; int ch=(i>>14)%56; int b=i/(56*16384);
  float v;
  if (ch<4) v=x[(size_t)(b*4+ch)*L_+p];
  else if (ch<36) v=img[(size_t)(b*32+ch-4)*L_+p];
  else v=oss[(size_t)(b*20+ch-36)*L_+p];
  xc[i]=v;
}

// ---- conv3x3 v3: 32x64 tile, 2x4 px/thread, b128 LDS reads, split-Cin(2) ----
// grid: x = 8 tiles (4 row x 2 col), y = Cout/NCO, z = b*2+ks
// scratch sc layout: [ks][b][co][128][128]
template<int NCO>
__global__ __launch_bounds__(256) void k_conv3v(const float* __restrict__ in, const float* __restrict__ wt,
                                                float* __restrict__ sc, int Cin, int Cout, int CIS){
  int tile=blockIdx.x; int th0=(tile>>1)*32, tw0=(tile&1)*64;
  int cg=blockIdx.y;
  int bz=blockIdx.z; int b=bz>>1, ks=bz&1;
  int cibase=ks*CIS;
  int cic=Cin-cibase; if (cic>CIS) cic=CIS;
  __shared__ float wlds[32][NCO][9];
  __shared__ float ibuf[2][34][68];   // stride 68: even (b128-aligned) + decorrelates banks
  int tid=threadIdx.x;
  for (int i=tid;i<cic*NCO*9;i+=256){
    int ci=i/(NCO*9), rem=i%(NCO*9), co=rem/9, q=rem%9;
    wlds[ci][co][q]=wt[(((size_t)(cg*NCO+co))*Cin + cibase+ci)*9+q];
  }
  auto stage=[&](int buf, int ci){
    const float* src=in+((size_t)b*Cin+cibase+ci)*L_;
    for (int i=tid;i<34*66;i+=256){
      int r=i/66, c=i%66;
      int gh=th0+r-1, gw=tw0+c-1;
      ibuf[buf][r][c]=(gh>=0&&gh<128&&gw>=0&&gw<128)?src[gh*128+gw]:0.f;
    }
  };
  stage(0,0);
  __syncthreads();
  float acc[NCO][8];
  #pragma unroll
  for (int co=0;co<NCO;co++)
    #pragma unroll
    for (int p2=0;p2<8;p2++) acc[co][p2]=0.f;
  int tr=2*(tid>>4), tc=4*(tid&15);
  for (int ci=0;ci<cic;ci++){
    int cur=ci&1;
    if (ci+1<cic) stage(cur^1, ci+1);
    float iv[4][8];
    #pragma unroll
    for (int r2=0;r2<4;r2++){
      *(float4*)&iv[r2][0]=*(const float4*)&ibuf[cur][tr+r2][tc];
      *(float4*)&iv[r2][4]=*(const float4*)&ibuf[cur][tr+r2][tc+4];
    }
    #pragma unroll
    for (int co=0;co<NCO;co++){
      const float* wp=wlds[ci][co];
      float w0=wp[0],w1=wp[1],w2=wp[2],w3=wp[3],w4=wp[4],w5=wp[5],w6=wp[6],w7=wp[7],w8=wp[8];
      #pragma unroll
      for (int pr=0;pr<2;pr++){
        #pragma unroll
        for (int pc2=0;pc2<4;pc2++){
          acc[co][pr*4+pc2]+= iv[pr][pc2]*w0+iv[pr][pc2+1]*w1+iv[pr][pc2+2]*w2
                             +iv[pr+1][pc2]*w3+iv[pr+1][pc2+1]*w4+iv[pr+1][pc2+2]*w5
                             +iv[pr+2][pc2]*w6+iv[pr+2][pc2+1]*w7+iv[pr+2][pc2+2]*w8;
        }
      }
    }
    __syncthreads();
  }
  #pragma unroll
  for (int co=0;co<NCO;co++){
    int gco=cg*NCO+co;
    float* dst=sc+((size_t)((ks*2+b)*Cout+gco))*L_+(size_t)(th0+tr)*128+tw0+tc;
    float4 a={acc[co][0],acc[co][1],acc[co][2],acc[co][3]};
    float4 c2={acc[co][4],acc[co][5],acc[co][6],acc[co][7]};
    *(float4*)dst=a;
    *(float4*)(dst+128)=c2;
  }
}

// vectorized epilogue: out = act( sc[0]+sc[1]+bias (+res) ), extra blocks zero zbuf
__global__ void k_epi4(const float4* __restrict__ sc, const float* __restrict__ bias,
                       const float4* __restrict__ res, float4* __restrict__ out, int Cout, int act,
                       float4* __restrict__ zbuf, int zn4){
  int n=2*Cout*4096;
  int i=blockIdx.x*256+threadIdx.x;
  if (i>=n){
    int z=i-n;
    if (z<zn4) zbuf[z]=make_float4(0.f,0.f,0.f,0.f);
    return;
  }
  int co=(i>>12)%Cout;
  float4 v=sc[i], w2=sc[(size_t)n+i];
  float bb=bias[co];
  float4 r;
  r.x=v.x+w2.x+bb; r.y=v.y+w2.y+bb; r.z=v.z+w2.z+bb; r.w=v.w+w2.w+bb;
  if (res){ float4 q=res[i]; r.x+=q.x; r.y+=q.y; r.z+=q.z; r.w+=q.w; }
  if (act){
    r.x=r.x>0.f?r.x:0.2f*r.x; r.y=r.y>0.f?r.y:0.2f*r.y;
    r.z=r.z>0.f?r.z:0.2f*r.z; r.w=r.w>0.f?r.w:0.2f*r.w;
  }
  out[i]=r;
}

// ---------------- FFT data consistency (3-way split) ----------------
__device__ __forceinline__ int rev7(int x){
  return ((x&1)<<6)|((x&2)<<4)|((x&4)<<2)|(x&8)|((x&16)>>2)|((x&32)>>4)|((x&64)>>6);
}

__global__ __launch_bounds__(256) void k_fftA(const float* __restrict__ x_ri, const float* __restrict__ sens,
                                              float* __restrict__ tmp){
  int blk=blockIdx.x; int b=blk>>7, coil=(blk>>3)&15, rg=blk&7;
  int r0=rg*16;
  __shared__ float Ar[16][128], Ai[16][128];
  __shared__ float twr[64], twi[64];
  int tid=threadIdx.x;
  if (tid<64){ float ang=-2.f*PI_F*(float)tid/128.f; twr[tid]=cosf(ang); twi[tid]=sinf(ang); }
  const float* srp=sens+(size_t)(b*32+2*coil)*L_;
  const float* sip=sens+(size_t)(b*32+2*coil+1)*L_;
  const float* xrp=x_ri+(size_t)(b*2)*L_;
  const float* xip=xrp+L_;
  for (int i=tid;i<2048;i+=256){
    int lr=i>>7, w=i&127; int gh=r0+lr; int idx=gh*128+w;
    float sg=((gh+w)&1)?-1.f:1.f;
    float sr=srp[idx],si=sip[idx],xr=xrp[idx],xi=xip[idx];
    Ar[lr][w]=sg*(sr*xr-si*xi);
    Ai[lr][w]=sg*(sr*xi+si*xr);
  }
  __syncthreads();
  for (int s=0;s<7;s++){
    int m=64>>s;
    for (int q=tid;q<1024;q+=256){
      int lr=q>>6, jj=q&63;
      int j=jj&(m-1), gg=jj>>(6-s);
      int kpos=(gg<<(7-s))+j;
      int tw=j<<s;
      float ur=Ar[lr][kpos],ui=Ai[lr][kpos],vr=Ar[lr][kpos+m],vi=Ai[lr][kpos+m];
      Ar[lr][kpos]=ur+vr; Ai[lr][kpos]=ui+vi;
      float dr=ur-vr,di=ui-vi,wr=twr[tw],wi=twi[tw];
      Ar[lr][kpos+m]=dr*wr-di*wi; Ai[lr][kpos+m]=dr*wi+di*wr;
    }
    __syncthreads();
  }
  float* tr=tmp+(size_t)(b*16+coil)*2*L_;
  float* ti=tr+L_;
  for (int i=tid;i<2048;i+=256){
    int lr=i>>7, w=i&127; int idx=(r0+lr)*128+w;
    tr[idx]=Ar[lr][w]; ti[idx]=Ai[lr][w];
  }
}

__global__ __launch_bounds__(256) void k_fftB(float* __restrict__ tmp, const float* __restrict__ ksp,
                                              const float* __restrict__ mask, const float* __restrict__ alpha_p){
  int blk=blockIdx.x; int b=blk>>7, coil=(blk>>3)&15, cg=blk&7;
  int c0=cg*16;
  __shared__ float Br[128][17], Bi[128][17];
  __shared__ float twr[64], twi[64];
  int tid=threadIdx.x;
  if (tid<64){ float ang=-2.f*PI_F*(float)tid/128.f; twr[tid]=cosf(ang); twi[tid]=sinf(ang); }
  float* tr=tmp+(size_t)(b*16+coil)*2*L_;
  float* ti=tr+L_;
  for (int i=tid;i<2048;i+=256){
    int r=i>>4, lc=i&15;
    Br[r][lc]=tr[r*128+c0+lc]; Bi[r][lc]=ti[r*128+c0+lc];
  }
  __syncthreads();
  for (int s=0;s<7;s++){
    int m=64>>s;
    for (int q=tid;q<1024;q+=256){
      int lc=q&15, jj=q>>4;
      int j=jj&(m-1), gg=jj>>(6-s);
      int kpos=(gg<<(7-s))+j;
      int tw=j<<s;
      float ur=Br[kpos][lc],ui=Bi[kpos][lc],vr=Br[kpos+m][lc],vi=Bi[kpos+m][lc];
      Br[kpos][lc]=ur+vr; Bi[kpos][lc]=ui+vi;
      float dr=ur-vr,di=ui-vi,wr=twr[tw],wi=twi[tw];
      Br[kpos+m][lc]=dr*wr-di*wi; Bi[kpos+m][lc]=dr*wi+di*wr;
    }
    __syncthreads();
  }
  float alpha=alpha_p[0];
  const float* krp=ksp+(size_t)(b*32+2*coil)*L_;
  const float* kip=ksp+(size_t)(b*32+2*coil+1)*L_;
  const float* mkp=mask+(size_t)b*L_;
  for (int i=tid;i<2048;i+=256){
    int r=i>>4, lc=i&15;
    int k1=rev7(r), k2=rev7(c0+lc);
    int kidx=k1*128+k2;
    float mv=mkp[kidx]*alpha;
    float sg=((k1+k2)&1)?-128.f:128.f;
    float kr=krp[kidx]*100.f*sg, ki=kip[kidx]*100.f*sg;
    Br[r][lc]=(1.f-mv)*Br[r][lc]+mv*kr;
    Bi[r][lc]=(1.f-mv)*Bi[r][lc]+mv*ki;
  }
  __syncthreads();
  for (int s=0;s<7;s++){
    int m=1<<s;
    for (int q=tid;q<1024;q+=256){
      int lc=q&15, jj=q>>4;
      int j=jj&(m-1), gg=jj>>s;
      int kpos=(gg<<(s+1))+j;
      int tw=j<<(6-s);
      float wr=twr[tw], wi=-twi[tw];
      float vr=Br[kpos+m][lc],vi=Bi[kpos+m][lc];
      float t2r=vr*wr-vi*wi, t2i=vr*wi+vi*wr;
      float ur=Br[kpos][lc],ui=Bi[kpos][lc];
      Br[kpos][lc]=ur+t2r; Bi[kpos][lc]=ui+t2i;
      Br[kpos+m][lc]=ur-t2r; Bi[kpos+m][lc]=ui-t2i;
    }
    __syncthreads();
  }
  for (int i=tid;i<2048;i+=256){
    int r=i>>4, lc=i&15;
    tr[r*128+c0+lc]=Br[r][lc]; ti[r*128+c0+lc]=Bi[r][lc];
  }
}

__global__ __launch_bounds__(256) void k_fftC(const float* __restrict__ tmp, const float* __restrict__ sens,
                                              float* __restrict__ acc){
  int blk=blockIdx.x; int b=blk>>7, coil=(blk>>3)&15, rg=blk&7;
  int r0=rg*16;
  __shared__ float Ar[16][128], Ai[16][128];
  __shared__ float twr[64], twi[64];
  int tid=threadIdx.x;
  if (tid<64){ float ang=-2.f*PI_F*(float)tid/128.f; twr[tid]=cosf(ang); twi[tid]=sinf(ang); }
  const float* tr=tmp+(size_t)(b*16+coil)*2*L_;
  const float* ti=tr+L_;
  for (int i=tid;i<2048;i+=256){
    int lr=i>>7, w=i&127; int idx=(r0+lr)*128+w;
    Ar[lr][w]=tr[idx]; Ai[lr][w]=ti[idx];
  }
  __syncthreads();
  for (int s=0;s<7;s++){
    int m=1<<s;
    for (int q=tid;q<1024;q+=256){
      int lr=q>>6, jj=q&63;
      int j=jj&(m-1), gg=jj>>s;
      int kpos=(gg<<(s+1))+j;
      int tw=j<<(6-s);
      float wr=twr[tw], wi=-twi[tw];
      float vr=Ar[lr][kpos+m],vi=Ai[lr][kpos+m];
      float t2r=vr*wr-vi*wi, t2i=vr*wi+vi*wr;
      float ur=Ar[lr][kpos],ui=Ai[lr][kpos];
      Ar[lr][kpos]=ur+t2r; Ai[lr][kpos]=ui+t2i;
      Ar[lr][kpos+m]=ur-t2r; Ai[lr][kpos+m]=ui-t2i;
    }
    __syncthreads();
  }
  const float* srp=sens+(size_t)(b*32+2*coil)*L_;
  const float* sip=sens+(size_t)(b*32+2*coil+1)*L_;
  float* accr=acc+(size_t)(b*2)*L_;
  float* acci=accr+L_;
  for (int i=tid;i<2048;i+=256){
    int lr=i>>7, w=i&127; int gh=r0+lr; int idx=gh*128+w;
    float sc=(((gh+w)&1)?-1.f:1.f)*(1.f/16384.f);
    float wr2=Ar[lr][w]*sc, wi2=Ai[lr][w]*sc;
    float sr=srp[idx], si=sip[idx];
    atomicAdd(&accr[idx], sr*wr2+si*wi2);
    atomicAdd(&acci[idx], sr*wi2-si*wr2);
  }
}

__global__ void k_mag(const float* __restrict__ acc, float* __restrict__ out){
  int i=blockIdx.x*256+threadIdx.x;
  int b=i>>14, p=i&16383;
  float re=acc[(size_t)(b*2)*L_+p], im=acc[(size_t)(b*2+1)*L_+p];
  out[i]=sqrtf(re*re+im*im+1e-12f);
}

extern "C" void kernel_launch(void* const* d_in, const int* in_sizes, int n_in,
                              void* d_out, int out_size, void* d_ws, size_t ws_size,
                              hipStream_t stream){
  const float* in_imgs=(const float*)d_in[0];
  const float* in_ksp=(const float*)d_in[1];
  const float* mask=(const float*)d_in[2];
  const float* sens=(const float*)d_in[3];
  const float* pe_ln1_g=(const float*)d_in[4];
  const float* pe_ln1_b=(const float*)d_in[5];
  const float* pe_w=(const float*)d_in[6];
  const float* pe_b=(const float*)d_in[7];
  const float* pe_ln2_g=(const float*)d_in[8];
  const float* pe_ln2_b=(const float*)d_in[9];
  const float* pos_emb=(const float*)d_in[10];
  const float* enc_aln_g=(const float*)d_in[11];
  const float* enc_aln_b=(const float*)d_in[12];
  const float* enc_wqkv=(const float*)d_in[13];
  const float* enc_wo=(const float*)d_in[14];
  const float* enc_bo=(const float*)d_in[15];
  const float* enc_fln_g=(const float*)d_in[16];
  const float* enc_fln_b=(const float*)d_in[17];
  const float* enc_w1=(const float*)d_in[18];
  const float* enc_b1=(const float*)d_in[19];
  const float* enc_w2=(const float*)d_in[20];
  const float* enc_b2=(const float*)d_in[21];
  const float* enc_ng=(const float*)d_in[22];
  const float* enc_nb=(const float*)d_in[23];
  const float* dec_pos=(const float*)d_in[24];
  const float* dec_aln_g=(const float*)d_in[25];
  const float* dec_aln_b=(const float*)d_in[26];
  const float* dec_wqkv=(const float*)d_in[27];
  const float* dec_wo=(const float*)d_in[28];
  const float* dec_bo=(const float*)d_in[29];
  const float* dec_fln_g=(const float*)d_in[30];
  const float* dec_fln_b=(const float*)d_in[31];
  const float* dec_w1=(const float*)d_in[32];
  const float* dec_b1=(const float*)d_in[33];
  const float* dec_w2=(const float*)d_in[34];
  const float* dec_b2=(const float*)d_in[35];
  const float* dec_ng=(const float*)d_in[36];
  const float* dec_nb=(const float*)d_in[37];
  const float* fin_w=(const float*)d_in[38];
  const float* fin_b=(const float*)d_in[39];
  const float* ss_in_w=(const float*)d_in[40];
  const float* ss_in_b=(const float*)d_in[41];
  const float* ss_conv_w=(const float*)d_in[42];
  const float* ss_conv_b=(const float*)d_in[43];
  const float* ss_xproj=(const float*)d_in[44];
  const float* ss_dt_w=(const float*)d_in[45];
  const float* ss_dt_b=(const float*)d_in[46];
  const float* ss_Alog=(const float*)d_in[47];
  const float* ss_D=(const float*)d_in[48];
  const float* ss_ln_g=(const float*)d_in[49];
  const float* ss_ln_b=(const float*)d_in[50];
  const float* ss_out_w=(const float*)d_in[51];
  const float* ss_out_b=(const float*)d_in[52];
  const float* head_w=(const float*)d_in[53];
  const float* head_b=(const float*)d_in[54];
  const float* res_w1=(const float*)d_in[55];
  const float* res_b1=(const float*)d_in[56];
  const float* res_w2=(const float*)d_in[57];
  const float* res_b2=(const float*)d_in[58];
  const float* tail_w=(const float*)d_in[59];
  const float* tail_b=(const float*)d_in[60];
  const float* dc_alpha=(const float*)d_in[61];

  char* ws=(char*)d_ws;
  size_t off=0;
  auto alloc=[&](size_t nfloats)->float*{ float* p=(float*)(ws+off); off+=((nfloats*4+255)/256)*256; return p; };
  float* xn   =alloc((size_t)32*32768);
  float* stats=alloc(64);
  float* tA   =alloc(32*512);
  float* tB   =alloc(32*512);
  float* aln  =alloc(32*512);
  float* qkv  =alloc(32*1536);
  float* attno=alloc(32*512);
  float* ffh  =alloc(32*3072);
  float* xup  =alloc((size_t)2*4*L_);
  float* xz   =alloc((size_t)2*64*L_);
  float* xs0  =alloc((size_t)2*32*L_);
  float* xs0T =alloc((size_t)2*32*L_);
  float* dbl  =alloc((size_t)2*4*L_*18);
  float* ys   =alloc((size_t)2*4*32*L_);
  float* smv  =alloc((size_t)8*128*256*2);
  float* prebuf=alloc((size_t)8*128*256);
  float* oss  =alloc((size_t)2*20*L_);
  float* xc   =alloc((size_t)2*56*L_);
  float* h0   =alloc((size_t)2*64*L_);
  float* tmpc =alloc((size_t)2*64*L_);
  float* csc  =alloc((size_t)2*2*64*L_);
  float* x_ri =alloc((size_t)2*2*L_);
  float* ftmp =alloc((size_t)32*2*L_);
  float* accb =alloc((size_t)2*2*L_);
  (void)ws_size; (void)in_sizes; (void)n_in; (void)out_size;

  // ---- patch embed + encoder/decoder ----
  hipMemsetAsync(stats, 0, 64*4, stream);
  k_pesum<<<256,256,0,stream>>>(in_imgs, stats);
  k_penorm<<<272,256,0,stream>>>(in_imgs, stats, pe_ln1_g, pe_ln1_b, xn, (float4*)tA, 4096);
  k_gemm_sk<256,0><<<dim3(8,128),256,0,stream>>>(xn, pe_w, pe_b, tA, 512, 32768);
  k_pe_post<<<32,256,0,stream>>>(tA, pe_ln2_g, pe_ln2_b, pos_emb);

  for (int i=0;i<4;i++){
    k_ln_tokz<<<80,256,0,stream>>>(tA, enc_aln_g+i*512, enc_aln_b+i*512, aln, (float4*)qkv, 12288);
    k_gemm_sk<64,0><<<dim3(24,8),256,0,stream>>>(aln, enc_wqkv+(size_t)i*512*1536, nullptr, qkv, 1536, 512);
    k_attn<<<16,256,0,stream>>>(qkv, attno);
    k_gemm_sk<64,0><<<dim3(8,8),256,0,stream>>>(attno, enc_wo+(size_t)i*512*512, enc_bo+i*512, tA, 512, 512);
    k_ln_tokz<<<96,256,0,stream>>>(tA, enc_fln_g+i*512, enc_fln_b+i*512, aln, (float4*)ffh, 16384);
    k_gemm_sk<64,0><<<dim3(32,8),256,0,stream>>>(aln, enc_w1+(size_t)i*512*2048, enc_b1+i*2048, ffh, 2048, 512);
    k_gemm_sk<64,1><<<dim3(8,32),256,0,stream>>>(ffh, enc_w2+(size_t)i*2048*512, enc_b2+i*512, tA, 512, 2048);
  }
  k_ln_tokz<<<32,256,0,stream>>>(tA, enc_ng, enc_nb, tA, nullptr, 0);
  k_addpos<<<64,256,0,stream>>>(tA, dec_pos, tB);
  k_ln_tokz<<<80,256,0,stream>>>(tB, dec_aln_g, dec_aln_b, aln, (float4*)qkv, 12288);
  k_gemm_sk<64,0><<<dim3(24,8),256,0,stream>>>(aln, dec_wqkv, nullptr, qkv, 1536, 512);
  k_attn<<<16,256,0,stream>>>(qkv, attno);
  k_gemm_sk<64,0><<<dim3(8,8),256,0,stream>>>(attno, dec_wo, dec_bo, tB, 512, 512);
  k_ln_tokz<<<128,256,0,stream>>>(tB, dec_fln_g, dec_fln_b, aln, (float4*)ffh, 24576);
  k_gemm_sk<64,0><<<dim3(48,8),256,0,stream>>>(aln, dec_w1, dec_b1, ffh, 3072, 512);
  k_gemm_sk<64,1><<<dim3(8,48),256,0,stream>>>(ffh, dec_w2, dec_b2, tB, 512, 3072);
  k_ln_tokz<<<160,256,0,stream>>>(tB, dec_ng, dec_nb, tB, (float4*)xup, 32768);
  k_gemm_sk<64,2><<<dim3(64,8),256,0,stream>>>(tB, fin_w, fin_b, xup, 4096, 512);

  // ---- SS2D ----
  k_xz<<<128,256,0,stream>>>(in_ksp, ss_in_w, ss_in_b, xz);
  k_dwconv<<<4096,256,0,stream>>>(xz, ss_conv_w, ss_conv_b, xs0);
  k_transpose<<<dim3(4,4,64),256,0,stream>>>(xs0, xs0T);
  k_dbl<<<dim3(64,8),256,0,stream>>>(xs0, xs0T, ss_xproj, dbl);
  k_scan1<<<1024,256,0,stream>>>(dbl, xs0, xs0T, ss_dt_w, ss_dt_b, ss_Alog, (float2*)smv);
  k_scan2<<<8,256,0,stream>>>((const float2*)smv, prebuf);
  k_scan3<<<1024,256,0,stream>>>(dbl, xs0, xs0T, ss_dt_w, ss_dt_b, ss_Alog, prebuf, ys);
  k_ycomb<<<256,256,0,stream>>>(ys, xz, xs0, ss_D, ss_ln_g, ss_ln_b, ss_out_w, ss_out_b, oss);

  // ---- conv head ----
  k_concat<<<7168,256,0,stream>>>(xup, in_imgs, oss, xc);
  k_conv3v<4><<<dim3(8,16,4),256,0,stream>>>(xc, head_w, csc, 56, 64, 28);
  k_epi4<<<2048,256,0,stream>>>((const float4*)csc, head_b, nullptr, (float4*)h0, 64, 1, nullptr, 0);
  for (int i=0;i<3;i++){
    k_conv3v<4><<<dim3(8,16,4),256,0,stream>>>(h0, res_w1+(size_t)i*64*64*9, csc, 64, 64, 32);
    k_epi4<<<2048,256,0,stream>>>((const float4*)csc, res_b1+i*64, nullptr, (float4*)tmpc, 64, 1, nullptr, 0);
    k_conv3v<4><<<dim3(8,16,4),256,0,stream>>>(tmpc, res_w2+(size_t)i*64*64*9, csc, 64, 64, 32);
    k_epi4<<<2048,256,0,stream>>>((const float4*)csc, res_b2+i*64, (const float4*)h0, (float4*)h0, 64, 1, nullptr, 0);
  }
  k_conv3v<2><<<dim3(8,1,4),256,0,stream>>>(h0, tail_w, csc, 64, 2, 32);
  k_epi4<<<128,256,0,stream>>>((const float4*)csc, tail_b, nullptr, (float4*)x_ri, 2, 0, (float4*)accb, 16384);

  // ---- FFT data consistency ----
  k_fftA<<<256,256,0,stream>>>(x_ri, sens, ftmp);
  k_fftB<<<256,256,0,stream>>>(ftmp, in_ksp, mask, dc_alpha);
  k_fftC<<<256,256,0,stream>>>(ftmp, sens, accb);
  k_mag<<<128,256,0,stream>>>(accb, (float*)d_out);
}